// Round 1
// baseline (629.243 us; speedup 1.0000x reference)
//
#include <hip/hip_runtime.h>

// GSSelfAttn: B=2048 windows, N=144 tokens, D=180, H=6 heads, hd=30.
// Fused per-window kernel: QKV proj -> attn(+rel bias) -> softmax -> PV -> out proj.
// bf16 MFMA (16x16x32) with fp32 accumulate everywhere.

typedef __bf16 bf16_t;
typedef __bf16 bf16x8 __attribute__((ext_vector_type(8)));
typedef float f32x4 __attribute__((ext_vector_type(4)));

#define MFMA16(a, b, c) __builtin_amdgcn_mfma_f32_16x16x32_bf16((a), (b), (c), 0, 0, 0)

static __device__ __forceinline__ f32x4 fzero4() {
    f32x4 z; z[0] = 0.f; z[1] = 0.f; z[2] = 0.f; z[3] = 0.f; return z;
}

// ---------------- pack kernel ----------------
// ws layout (bytes):
//   Wqkv  @ 0      : [h][kt6][nt6][lane64][j8] bf16      = 221184 B
//   Wp    @ 221184 : [kt6][nt12][lane64][j8]  bf16       =  73728 B
//   BIASb @ 294912 : [h][q144][k144]          bf16       = 248832 B
//   bqkv  @ 543744 : [h][c96]                 fp32       =   2304 B
__global__ void pack_kernel(const float* __restrict__ wq, const float* __restrict__ bq,
                            const float* __restrict__ wk, const float* __restrict__ bk,
                            const float* __restrict__ wv, const float* __restrict__ bv,
                            const float* __restrict__ wp, const float* __restrict__ bt,
                            bf16_t* __restrict__ Wqkv, bf16_t* __restrict__ Wp,
                            bf16_t* __restrict__ BIASb, float* __restrict__ bqkv)
{
    const int t = blockIdx.x * blockDim.x + threadIdx.x;
    const int stride = gridDim.x * blockDim.x;
    const float scale = 0.18257418583505536f;   // 30^-0.5, folded into Q path

    // Wqkv fragments: kin padded 180->192, per-head cols: [Q32|K32|V32], d padded 30->32
    for (int i = t; i < 6 * 6 * 6 * 512; i += stride) {
        int j = i & 7, lane = (i >> 3) & 63;
        int f = i >> 9;               // [h][kt][nt]
        int nt = f % 6, kt = (f / 6) % 6, h = f / 36;
        int kin = kt * 32 + (lane >> 4) * 8 + j;
        int c = nt * 16 + (lane & 15);       // 0..95
        int sec = c >> 5, d = c & 31;
        float v = 0.f;
        if (kin < 180 && d < 30) {
            int col = h * 30 + d;
            if (sec == 0)      v = wq[kin * 180 + col] * scale;
            else if (sec == 1) v = wk[kin * 180 + col];
            else               v = wv[kin * 180 + col];
        }
        Wqkv[i] = (bf16_t)v;
    }
    // Wp fragments: K index = h*32+d (matches O tile layout), pad rows d>=30 zero
    for (int i = t; i < 6 * 12 * 512; i += stride) {
        int j = i & 7, lane = (i >> 3) & 63;
        int f = i >> 9;               // [kt][nt]
        int nt = f % 12, kt = f / 12;
        int kin = kt * 32 + (lane >> 4) * 8 + j;
        int hh = kin >> 5, d = kin & 31;
        int cout = nt * 16 + (lane & 15);
        float v = 0.f;
        if (d < 30 && cout < 180) v = wp[(hh * 30 + d) * 180 + cout];
        Wp[i] = (bf16_t)v;
    }
    // relative-position bias, fully materialized per head
    for (int i = t; i < 6 * 144 * 144; i += stride) {
        int k = i % 144, q = (i / 144) % 144, h = i / (144 * 144);
        int qi = q / 12, qj = q % 12, ki = k / 12, kj = k % 12;
        int rel = (qi - ki + 11) * 23 + (qj - kj + 11);
        BIASb[i] = (bf16_t)bt[rel * 6 + h];
    }
    // packed qkv bias (scale folded into q part)
    for (int i = t; i < 576; i += stride) {
        int c = i % 96, h = i / 96;
        int sec = c >> 5, d = c & 31;
        float v = 0.f;
        if (d < 30) {
            if (sec == 0)      v = bq[h * 30 + d] * scale;
            else if (sec == 1) v = bk[h * 30 + d];
            else               v = bv[h * 30 + d];
        }
        bqkv[i] = v;
    }
}

// ---------------- fused attention kernel ----------------
// block = 576 threads = 9 waves; wave w owns M-strip rows [16w, 16w+16)
// LDS map (total 132864 B):
//   O    @ 0      : [144][192] bf16, stride 384 B, swizzle byte^=((row&7)<<4)
//   Q    @ 55296  : [144][32]  bf16, stride 64 B,  swizzle byte^=((row&6)<<3)
//   K    @ 64512  : [144][32]  bf16, same swizzle
//   Vt   @ 73728  : [32][168]  bf16 (d-major, token cols padded/zeroed 144..159)
//   P/W  @ 84480  : per-wave [16][168] bf16 P strips (9*5376=48384 B);
//                   doubles as Wqkv head stage (36864 B).
//   Wp stage aliases Q..P region (73728 B <= 77568 B) after the head loop.
__global__ __launch_bounds__(576, 2)
void attn_kernel(const float* __restrict__ gs,
                 const bf16_t* __restrict__ Wqkv, const bf16_t* __restrict__ Wp,
                 const bf16_t* __restrict__ BIASb, const float* __restrict__ bqkv,
                 const float* __restrict__ bp, float* __restrict__ out)
{
    __shared__ __align__(16) unsigned char smem[132864];

    const int tid = threadIdx.x;
    const int lane = tid & 63;
    const int wv = tid >> 6;          // wave id = M-strip 0..8
    const int l15 = lane & 15;
    const int lg = lane >> 4;         // 0..3
    const int win = blockIdx.x;
    const float* __restrict__ gsw = gs + (size_t)win * 25920;

    constexpr int O_BASE = 0;
    constexpr int U_BASE = 55296;
    constexpr int Q_BASE = U_BASE;
    constexpr int K_BASE = U_BASE + 9216;
    constexpr int VT_BASE = U_BASE + 18432;
    constexpr int P_BASE = U_BASE + 29184;
    constexpr int W_BASE = P_BASE;    // per-head weight stage aliases P strips

    // ---- gs A-fragments into registers: row = 16*wv + l15, k-tile kt ----
    bf16x8 xa[6];
    {
        const int row = wv * 16 + l15;
        const float* __restrict__ grow = gsw + row * 180;
        #pragma unroll
        for (int kt = 0; kt < 6; ++kt) {
            const int c0 = kt * 32 + lg * 8;
            bf16x8 v;
            #pragma unroll
            for (int j = 0; j < 8; ++j) {
                int c = c0 + j;
                float f = (c < 180) ? grow[c] : 0.f;
                v[j] = (bf16_t)f;
            }
            xa[kt] = v;
        }
    }
    // zero Vt pad token-cols 144..159 once (never rewritten)
    if (tid < 512) {
        int d = tid >> 4, c = 144 + (tid & 15);
        *(bf16_t*)(smem + VT_BASE + d * 336 + c * 2) = (bf16_t)0.f;
    }

    for (int h = 0; h < 6; ++h) {
        __syncthreads();              // prior head fully consumed P/Q/K/Vt
        // ---- stage this head's packed weights (36864 B) ----
        {
            const char* __restrict__ src = (const char*)Wqkv + h * 36864;
            #pragma unroll
            for (int i = 0; i < 4; ++i) {
                int off = (tid + i * 576) * 16;
                *(int4*)(smem + W_BASE + off) = *(const int4*)(src + off);
            }
        }
        __syncthreads();

        // ---- QKV GEMM: acc[nt] = X(strip) @ W[:, nt] ----
        f32x4 acc[6];
        #pragma unroll
        for (int nt = 0; nt < 6; ++nt) acc[nt] = fzero4();
        #pragma unroll
        for (int kt = 0; kt < 6; ++kt) {
            #pragma unroll
            for (int nt = 0; nt < 6; ++nt) {
                bf16x8 bw = *(const bf16x8*)(smem + W_BASE + ((kt * 6 + nt) * 64 + lane) * 16);
                acc[nt] = MFMA16(xa[kt], bw, acc[nt]);
            }
        }
        __syncthreads();              // everyone done reading W (P region now writable later)

        // ---- scatter QKV to LDS (bf16): Q,K row-major swizzled; V transposed ----
        {
            const int row0 = wv * 16 + lg * 4;
            #pragma unroll
            for (int nt = 0; nt < 6; ++nt) {
                const int c = nt * 16 + l15;         // 0..95
                const float bias = bqkv[h * 96 + c];
                const int sec = nt >> 1;
                const int d32 = ((nt & 1) << 4) + l15;
                #pragma unroll
                for (int r = 0; r < 4; ++r) {
                    const int rr = row0 + r;
                    const bf16_t bvl = (bf16_t)(acc[nt][r] + bias);
                    if (sec == 0)
                        *(bf16_t*)(smem + Q_BASE + rr * 64 + ((d32 * 2) ^ ((rr & 6) << 3))) = bvl;
                    else if (sec == 1)
                        *(bf16_t*)(smem + K_BASE + rr * 64 + ((d32 * 2) ^ ((rr & 6) << 3))) = bvl;
                    else
                        *(bf16_t*)(smem + VT_BASE + d32 * 336 + rr * 2) = bvl;
                }
            }
        }
        __syncthreads();              // QKV visible to all waves

        // ---- S = Q K^T + bias ; softmax ; P -> LDS ; PV ; accumulate O ----
        {
            f32x4 s[9];
            const int qrow = wv * 16 + l15;
            bf16x8 aq = *(const bf16x8*)(smem + Q_BASE + qrow * 64 + ((lg * 16) ^ ((qrow & 6) << 3)));
            #pragma unroll
            for (int nt = 0; nt < 9; ++nt) {
                const int krow = nt * 16 + l15;
                bf16x8 bk = *(const bf16x8*)(smem + K_BASE + krow * 64 + ((lg * 16) ^ ((krow & 6) << 3)));
                s[nt] = MFMA16(aq, bk, fzero4());
            }
            // add relative-position bias (D-layout: row=(lg*4+r), col=nt*16+l15)
            const bf16_t* __restrict__ bb = BIASb + (size_t)(h * 144 + wv * 16 + lg * 4) * 144 + l15;
            #pragma unroll
            for (int nt = 0; nt < 9; ++nt)
                #pragma unroll
                for (int r = 0; r < 4; ++r)
                    s[nt][r] += (float)bb[r * 144 + nt * 16];

            // wave-local softmax over 144 cols (9 tiles x 16 lanes of the group)
            float rinv[4];
            #pragma unroll
            for (int r = 0; r < 4; ++r) {
                float m = s[0][r];
                #pragma unroll
                for (int nt = 1; nt < 9; ++nt) m = fmaxf(m, s[nt][r]);
                m = fmaxf(m, __shfl_xor(m, 1, 64));
                m = fmaxf(m, __shfl_xor(m, 2, 64));
                m = fmaxf(m, __shfl_xor(m, 4, 64));
                m = fmaxf(m, __shfl_xor(m, 8, 64));
                float sum = 0.f;
                #pragma unroll
                for (int nt = 0; nt < 9; ++nt) {
                    float p = exp2f((s[nt][r] - m) * 1.4426950408889634f);
                    s[nt][r] = p;
                    sum += p;
                }
                sum += __shfl_xor(sum, 1, 64);
                sum += __shfl_xor(sum, 2, 64);
                sum += __shfl_xor(sum, 4, 64);
                sum += __shfl_xor(sum, 8, 64);
                rinv[r] = 1.f / sum;   // denominator deferred to O epilogue
            }

            // write P strip (wave-private [16][168] bf16)
            char* pb = (char*)smem + P_BASE + wv * 5376;
            #pragma unroll
            for (int nt = 0; nt < 9; ++nt)
                #pragma unroll
                for (int r = 0; r < 4; ++r)
                    *(bf16_t*)(pb + (lg * 4 + r) * 336 + (nt * 16 + l15) * 2) = (bf16_t)s[nt][r];
            // zero P pad cols 144..159 (W stage clobbers them each head)
            *(unsigned long long*)(pb + l15 * 336 + 288 + lg * 8) = 0ull;

            // PV: O(strip)[16x32] = P[16x160] @ Vt^T, K-tiles of 32
            f32x4 o[2];
            o[0] = fzero4(); o[1] = fzero4();
            #pragma unroll
            for (int kt = 0; kt < 5; ++kt) {
                bf16x8 ap = *(const bf16x8*)(pb + l15 * 336 + kt * 64 + lg * 16);
                #pragma unroll
                for (int nv = 0; nv < 2; ++nv) {
                    bf16x8 bvv = *(const bf16x8*)(smem + VT_BASE + (nv * 16 + l15) * 336 + kt * 64 + lg * 16);
                    o[nv] = MFMA16(ap, bvv, o[nv]);
                }
            }
            // accumulate head slice into O tile (cols h*32 .. h*32+31; 30,31 are zero)
            #pragma unroll
            for (int nv = 0; nv < 2; ++nv) {
                const int col = h * 32 + nv * 16 + l15;
                #pragma unroll
                for (int r = 0; r < 4; ++r) {
                    const int rr = wv * 16 + lg * 4 + r;
                    *(bf16_t*)(smem + O_BASE + rr * 384 + ((col * 2) ^ ((rr & 7) << 4))) =
                        (bf16_t)(o[nv][r] * rinv[r]);
                }
            }
        }
    }

    __syncthreads();                  // all O written, Q/K/Vt/P dead
    // ---- stage Wp (73728 B) over the dead Q..P region ----
    {
        #pragma unroll
        for (int i = 0; i < 8; ++i) {
            int off = (tid + i * 576) * 16;
            *(int4*)(smem + U_BASE + off) = *(const int4*)((const char*)Wp + off);
        }
    }
    __syncthreads();

    // ---- output projection: out = O @ Wp + bp (fp32 store) ----
    {
        f32x4 accp[12];
        #pragma unroll
        for (int nt = 0; nt < 12; ++nt) accp[nt] = fzero4();
        const int orow = wv * 16 + l15;
        #pragma unroll
        for (int kt = 0; kt < 6; ++kt) {
            bf16x8 ao = *(const bf16x8*)(smem + O_BASE + orow * 384 +
                                         ((kt * 64 + lg * 16) ^ ((orow & 7) << 4)));
            #pragma unroll
            for (int nt = 0; nt < 12; ++nt) {
                bf16x8 bw = *(const bf16x8*)(smem + U_BASE + ((kt * 12 + nt) * 64 + lane) * 16);
                accp[nt] = MFMA16(ao, bw, accp[nt]);
            }
        }
        float* __restrict__ og = out + (size_t)win * 25920;
        #pragma unroll
        for (int nt = 0; nt < 12; ++nt) {
            const int col = nt * 16 + l15;
            if (col < 180) {
                const float bias = bp[col];
                #pragma unroll
                for (int r = 0; r < 4; ++r) {
                    const int row = wv * 16 + lg * 4 + r;
                    og[row * 180 + col] = accp[nt][r] + bias;
                }
            }
        }
    }
}

extern "C" void kernel_launch(void* const* d_in, const int* in_sizes, int n_in,
                              void* d_out, int out_size, void* d_ws, size_t ws_size,
                              hipStream_t stream) {
    const float* gs = (const float*)d_in[0];
    const float* wq = (const float*)d_in[1];
    const float* bq = (const float*)d_in[2];
    const float* wk = (const float*)d_in[3];
    const float* bk = (const float*)d_in[4];
    const float* wv = (const float*)d_in[5];
    const float* bv = (const float*)d_in[6];
    const float* wp = (const float*)d_in[7];
    const float* bp = (const float*)d_in[8];
    const float* bt = (const float*)d_in[9];

    char* ws = (char*)d_ws;
    bf16_t* Wqkv  = (bf16_t*)(ws);
    bf16_t* Wp    = (bf16_t*)(ws + 221184);
    bf16_t* BIASb = (bf16_t*)(ws + 294912);
    float*  bqkv  = (float*)(ws + 543744);

    pack_kernel<<<256, 256, 0, stream>>>(wq, bq, wk, bk, wv, bv, wp, bt,
                                         Wqkv, Wp, BIASb, bqkv);
    attn_kernel<<<2048, 576, 0, stream>>>(gs, Wqkv, Wp, BIASb, bqkv, bp, (float*)d_out);
}

// Round 2
// 548.607 us; speedup vs baseline: 1.1470x; 1.1470x over previous
//
#include <hip/hip_runtime.h>

// GSSelfAttn: B=2048 windows, N=144 tokens, D=180, H=6 heads, hd=30.
// Fused per-window kernel: QKV proj -> attn(+rel bias) -> softmax -> PV -> out proj.
// bf16 MFMA (16x16x32) with fp32 accumulate everywhere.
// R2: 77.6KB LDS (2 blocks/CU), O kept in per-wave A-fragment registers via
// per-head strip transpose, fragment-layout bias table, vectorized gs loads,
// 3 barriers/head, setprio around MFMA clusters.

typedef __bf16 bf16_t;
typedef __bf16 bf16x8 __attribute__((ext_vector_type(8)));
typedef __bf16 bf16x4 __attribute__((ext_vector_type(4)));
typedef float f32x4 __attribute__((ext_vector_type(4)));

#define MFMA16(a, b, c) __builtin_amdgcn_mfma_f32_16x16x32_bf16((a), (b), (c), 0, 0, 0)

static __device__ __forceinline__ f32x4 fzero4() {
    f32x4 z; z[0] = 0.f; z[1] = 0.f; z[2] = 0.f; z[3] = 0.f; return z;
}

// ---------------- pack kernel ----------------
// ws layout (bytes):
//   Wqkv  @ 0      : [h][kt6][nt6][lane64][j8] bf16      = 221184 B
//   Wp    @ 221184 : [kt6][nt12][lane64][j8]  bf16       =  73728 B
//   BIASf @ 294912 : [h][wv9][nt9][lane64][r4] bf16      = 248832 B (fragment layout)
//   bqkv  @ 543744 : [h][c96]                 fp32       =   2304 B
__global__ void pack_kernel(const float* __restrict__ wq, const float* __restrict__ bq,
                            const float* __restrict__ wk, const float* __restrict__ bk,
                            const float* __restrict__ wv, const float* __restrict__ bv,
                            const float* __restrict__ wp, const float* __restrict__ bt,
                            bf16_t* __restrict__ Wqkv, bf16_t* __restrict__ Wp,
                            bf16_t* __restrict__ BIASf, float* __restrict__ bqkv)
{
    const int t = blockIdx.x * blockDim.x + threadIdx.x;
    const int stride = gridDim.x * blockDim.x;
    const float scale = 0.18257418583505536f;   // 30^-0.5, folded into Q path

    // Wqkv fragments: kin padded 180->192, per-head cols: [Q32|K32|V32], d padded 30->32
    for (int i = t; i < 6 * 6 * 6 * 512; i += stride) {
        int j = i & 7, lane = (i >> 3) & 63;
        int f = i >> 9;               // [h][kt][nt]
        int nt = f % 6, kt = (f / 6) % 6, h = f / 36;
        int kin = kt * 32 + (lane >> 4) * 8 + j;
        int c = nt * 16 + (lane & 15);       // 0..95
        int sec = c >> 5, d = c & 31;
        float v = 0.f;
        if (kin < 180 && d < 30) {
            int col = h * 30 + d;
            if (sec == 0)      v = wq[kin * 180 + col] * scale;
            else if (sec == 1) v = wk[kin * 180 + col];
            else               v = wv[kin * 180 + col];
        }
        Wqkv[i] = (bf16_t)v;
    }
    // Wp fragments: K index = h*32+d (matches O fragment layout), pad rows d>=30 zero
    for (int i = t; i < 6 * 12 * 512; i += stride) {
        int j = i & 7, lane = (i >> 3) & 63;
        int f = i >> 9;               // [kt][nt]
        int nt = f % 12, kt = f / 12;
        int kin = kt * 32 + (lane >> 4) * 8 + j;
        int hh = kin >> 5, d = kin & 31;
        int cout = nt * 16 + (lane & 15);
        float v = 0.f;
        if (d < 30 && cout < 180) v = wp[(hh * 30 + d) * 180 + cout];
        Wp[i] = (bf16_t)v;
    }
    // relative-position bias in S-fragment layout:
    // BIASf[((h*9+wv)*9+nt)*64 + lane][r] = bias[h][q = wv*16+lg*4+r][k = nt*16+l15]
    for (int i = t; i < 6 * 9 * 9 * 64; i += stride) {
        int lane = i & 63;
        int f = i >> 6;               // [h][wv][nt]
        int nt = f % 9, wvq = (f / 9) % 9, h = f / 81;
        int k = nt * 16 + (lane & 15);
        int ki = k / 12, kj = k % 12;
        #pragma unroll
        for (int r = 0; r < 4; ++r) {
            int q = wvq * 16 + (lane >> 4) * 4 + r;
            int qi = q / 12, qj = q % 12;
            int rel = (qi - ki + 11) * 23 + (qj - kj + 11);
            BIASf[i * 4 + r] = (bf16_t)bt[rel * 6 + h];
        }
    }
    // packed qkv bias (scale folded into q part)
    for (int i = t; i < 576; i += stride) {
        int c = i % 96, h = i / 96;
        int sec = c >> 5, d = c & 31;
        float v = 0.f;
        if (d < 30) {
            if (sec == 0)      v = bq[h * 30 + d] * scale;
            else if (sec == 1) v = bk[h * 30 + d];
            else               v = bv[h * 30 + d];
        }
        bqkv[i] = v;
    }
}

// ---------------- fused attention kernel ----------------
// block = 576 threads = 9 waves; wave w owns M-strip rows [16w, 16w+16)
// LDS map (total 77568 B -> 2 blocks/CU):
//   W/P  @ 0     : max(Wqkv head stage 36864, 9 per-wave P strips [16][168] = 48384)
//   Q    @ 48384 : [144][32] bf16, stride 64 B, swizzle byte^=((row&6)<<3)   (9216 B)
//   K    @ 57600 : same                                                       (9216 B)
//   Vt   @ 66816 : [32][168] bf16 (d-major, token cols 144..159 zeroed)      (10752 B)
// Epilogue: Wp stage (73728 B) aliases base 0 (everything dead).
// O never hits shared LDS: per head, the 16x32 head slice is transposed through
// the wave-private P strip into persistent A-fragment registers ao[h].
__global__ __launch_bounds__(576, 5)
void attn_kernel(const float* __restrict__ gs,
                 const bf16_t* __restrict__ Wqkv, const bf16_t* __restrict__ Wp,
                 const bf16_t* __restrict__ BIASf, const float* __restrict__ bqkv,
                 const float* __restrict__ bp, float* __restrict__ out)
{
    __shared__ __align__(16) unsigned char smem[77568];

    const int tid = threadIdx.x;
    const int lane = tid & 63;
    const int wv = tid >> 6;          // wave id = M-strip 0..8
    const int l15 = lane & 15;
    const int lg = lane >> 4;         // 0..3
    const int win = blockIdx.x;
    const float* __restrict__ gsw = gs + (size_t)win * 25920;

    constexpr int WP_BASE = 0;
    constexpr int Q_BASE  = 48384;
    constexpr int K_BASE  = 57600;
    constexpr int VT_BASE = 66816;

    // ---- gs A-fragments into registers: row = 16*wv + l15, k-tile kt ----
    bf16x8 xa[6];
    {
        const int row = wv * 16 + l15;
        const float4* __restrict__ g4 = (const float4*)(gsw + row * 180);
        #pragma unroll
        for (int kt = 0; kt < 6; ++kt) {
            const int c0 = kt * 32 + lg * 8;
            float4 lo = {0.f, 0.f, 0.f, 0.f}, hi = {0.f, 0.f, 0.f, 0.f};
            if (c0 + 4 <= 180) lo = g4[c0 >> 2];
            if (c0 + 8 <= 180) hi = g4[(c0 >> 2) + 1];
            bf16x8 v;
            v[0] = (bf16_t)lo.x; v[1] = (bf16_t)lo.y; v[2] = (bf16_t)lo.z; v[3] = (bf16_t)lo.w;
            v[4] = (bf16_t)hi.x; v[5] = (bf16_t)hi.y; v[6] = (bf16_t)hi.z; v[7] = (bf16_t)hi.w;
            xa[kt] = v;
        }
    }
    // zero Vt pad token-cols 144..159 once (never clobbered afterwards)
    if (tid < 512) {
        int d = tid >> 4, c = 144 + (tid & 15);
        *(bf16_t*)(smem + VT_BASE + d * 336 + c * 2) = (bf16_t)0.f;
    }

    bf16x8 ao[6];                     // per-head O A-fragments (persistent)

    #pragma unroll
    for (int h = 0; h < 6; ++h) {
        __syncthreads();              // prior head's Q/K/Vt/P fully consumed
        // ---- stage this head's packed weights (36864 B) ----
        {
            const char* __restrict__ src = (const char*)Wqkv + h * 36864;
            #pragma unroll
            for (int i = 0; i < 4; ++i) {
                const int off = (tid + i * 576) * 16;
                *(int4*)(smem + WP_BASE + off) = *(const int4*)(src + off);
            }
        }
        __syncthreads();

        // ---- QKV GEMM: acc[nt] = X(strip) @ W[:, nt] ----
        f32x4 acc[6];
        #pragma unroll
        for (int nt = 0; nt < 6; ++nt) acc[nt] = fzero4();
        __builtin_amdgcn_s_setprio(1);
        #pragma unroll
        for (int kt = 0; kt < 6; ++kt) {
            #pragma unroll
            for (int nt = 0; nt < 6; ++nt) {
                bf16x8 bw = *(const bf16x8*)(smem + WP_BASE + ((kt * 6 + nt) * 64 + lane) * 16);
                acc[nt] = MFMA16(xa[kt], bw, acc[nt]);
            }
        }
        __builtin_amdgcn_s_setprio(0);

        // ---- scatter QKV to LDS (bf16): Q,K row-major swizzled; V transposed ----
        {
            const int row0 = wv * 16 + lg * 4;
            #pragma unroll
            for (int nt = 0; nt < 6; ++nt) {
                const int c = nt * 16 + l15;         // 0..95
                const float bias = bqkv[h * 96 + c];
                const int sec = nt >> 1;
                const int d32 = ((nt & 1) << 4) + l15;
                #pragma unroll
                for (int r = 0; r < 4; ++r) {
                    const int rr = row0 + r;
                    const bf16_t bvl = (bf16_t)(acc[nt][r] + bias);
                    if (sec == 0)
                        *(bf16_t*)(smem + Q_BASE + rr * 64 + ((d32 * 2) ^ ((rr & 6) << 3))) = bvl;
                    else if (sec == 1)
                        *(bf16_t*)(smem + K_BASE + rr * 64 + ((d32 * 2) ^ ((rr & 6) << 3))) = bvl;
                    else
                        *(bf16_t*)(smem + VT_BASE + d32 * 336 + rr * 2) = bvl;
                }
            }
        }
        __syncthreads();              // QKV visible to all waves (also: W reads done)

        // ---- S = Q K^T + bias ; softmax ; P -> strip ; PV ; O -> ao[h] ----
        {
            f32x4 s[9];
            const int qrow = wv * 16 + l15;
            bf16x8 aq = *(const bf16x8*)(smem + Q_BASE + qrow * 64 + ((lg * 16) ^ ((qrow & 6) << 3)));
            __builtin_amdgcn_s_setprio(1);
            #pragma unroll
            for (int nt = 0; nt < 9; ++nt) {
                const int krow = nt * 16 + l15;
                bf16x8 bkf = *(const bf16x8*)(smem + K_BASE + krow * 64 + ((lg * 16) ^ ((krow & 6) << 3)));
                s[nt] = MFMA16(aq, bkf, fzero4());
            }
            __builtin_amdgcn_s_setprio(0);
            // add relative-position bias (fragment-layout table, one 8B load per nt)
            #pragma unroll
            for (int nt = 0; nt < 9; ++nt) {
                bf16x4 b4 = *(const bf16x4*)(BIASf + (size_t)((((h * 9 + wv) * 9 + nt) * 64 + lane) * 4));
                #pragma unroll
                for (int r = 0; r < 4; ++r) s[nt][r] += (float)b4[r];
            }

            // wave-local softmax over 144 cols (reduce across 16 lanes of the group)
            float rinv[4];
            #pragma unroll
            for (int r = 0; r < 4; ++r) {
                float m = s[0][r];
                #pragma unroll
                for (int nt = 1; nt < 9; ++nt) m = fmaxf(m, s[nt][r]);
                m = fmaxf(m, __shfl_xor(m, 1, 64));
                m = fmaxf(m, __shfl_xor(m, 2, 64));
                m = fmaxf(m, __shfl_xor(m, 4, 64));
                m = fmaxf(m, __shfl_xor(m, 8, 64));
                float sum = 0.f;
                #pragma unroll
                for (int nt = 0; nt < 9; ++nt) {
                    float p = exp2f((s[nt][r] - m) * 1.4426950408889634f);
                    s[nt][r] = p;
                    sum += p;
                }
                sum += __shfl_xor(sum, 1, 64);
                sum += __shfl_xor(sum, 2, 64);
                sum += __shfl_xor(sum, 4, 64);
                sum += __shfl_xor(sum, 8, 64);
                rinv[r] = 1.f / sum;   // denominator deferred to O epilogue
            }

            // write P strip (wave-private [16][168] bf16, stride 336 B)
            char* pb = (char*)smem + WP_BASE + wv * 5376;
            #pragma unroll
            for (int nt = 0; nt < 9; ++nt)
                #pragma unroll
                for (int r = 0; r < 4; ++r)
                    *(bf16_t*)(pb + (lg * 4 + r) * 336 + (nt * 16 + l15) * 2) = (bf16_t)s[nt][r];
            // (cols 144..159 of P may be garbage; Vt pad cols are zero, so PV unaffected)

            // PV: O(strip)[16x32] = P[16x160] @ Vt^T, K-tiles of 32
            f32x4 o0 = fzero4(), o1 = fzero4();
            __builtin_amdgcn_s_setprio(1);
            #pragma unroll
            for (int kt = 0; kt < 5; ++kt) {
                bf16x8 ap = *(const bf16x8*)(pb + l15 * 336 + kt * 64 + lg * 16);
                bf16x8 bv0 = *(const bf16x8*)(smem + VT_BASE + l15 * 336 + kt * 64 + lg * 16);
                bf16x8 bv1 = *(const bf16x8*)(smem + VT_BASE + (16 + l15) * 336 + kt * 64 + lg * 16);
                o0 = MFMA16(ap, bv0, o0);
                o1 = MFMA16(ap, bv1, o1);
            }
            __builtin_amdgcn_s_setprio(0);

            // transpose 16x32 head slice through own strip -> A-fragment regs
            // (in-wave DS ordering: these writes are issued after all PV reads)
            #pragma unroll
            for (int r = 0; r < 4; ++r) {
                *(bf16_t*)(pb + (lg * 4 + r) * 64 + l15 * 2)      = (bf16_t)(o0[r] * rinv[r]);
                *(bf16_t*)(pb + (lg * 4 + r) * 64 + 32 + l15 * 2) = (bf16_t)(o1[r] * rinv[r]);
            }
            ao[h] = *(const bf16x8*)(pb + l15 * 64 + lg * 16);
        }
    }

    __syncthreads();                  // all LDS dead; ao[] holds O fragments
    // ---- stage Wp (73728 B) over base 0 ----
    {
        #pragma unroll
        for (int i = 0; i < 8; ++i) {
            const int off = (tid + i * 576) * 16;
            *(int4*)(smem + off) = *(const int4*)((const char*)Wp + off);
        }
    }
    __syncthreads();

    // ---- output projection: out = O @ Wp + bp (fp32 store) ----
    {
        f32x4 accp[12];
        #pragma unroll
        for (int nt = 0; nt < 12; ++nt) accp[nt] = fzero4();
        __builtin_amdgcn_s_setprio(1);
        #pragma unroll
        for (int kt = 0; kt < 6; ++kt) {
            #pragma unroll
            for (int nt = 0; nt < 12; ++nt) {
                bf16x8 bw = *(const bf16x8*)(smem + ((kt * 12 + nt) * 64 + lane) * 16);
                accp[nt] = MFMA16(ao[kt], bw, accp[nt]);
            }
        }
        __builtin_amdgcn_s_setprio(0);
        float* __restrict__ og = out + (size_t)win * 25920;
        #pragma unroll
        for (int nt = 0; nt < 12; ++nt) {
            const int col = nt * 16 + l15;
            if (col < 180) {
                const float bias = bp[col];
                #pragma unroll
                for (int r = 0; r < 4; ++r) {
                    const int row = wv * 16 + lg * 4 + r;
                    og[row * 180 + col] = accp[nt][r] + bias;
                }
            }
        }
    }
}

extern "C" void kernel_launch(void* const* d_in, const int* in_sizes, int n_in,
                              void* d_out, int out_size, void* d_ws, size_t ws_size,
                              hipStream_t stream) {
    const float* gs = (const float*)d_in[0];
    const float* wq = (const float*)d_in[1];
    const float* bq = (const float*)d_in[2];
    const float* wk = (const float*)d_in[3];
    const float* bk = (const float*)d_in[4];
    const float* wv = (const float*)d_in[5];
    const float* bv = (const float*)d_in[6];
    const float* wp = (const float*)d_in[7];
    const float* bp = (const float*)d_in[8];
    const float* bt = (const float*)d_in[9];

    char* ws = (char*)d_ws;
    bf16_t* Wqkv  = (bf16_t*)(ws);
    bf16_t* Wp    = (bf16_t*)(ws + 221184);
    bf16_t* BIASf = (bf16_t*)(ws + 294912);
    float*  bqkv  = (float*)(ws + 543744);

    pack_kernel<<<256, 256, 0, stream>>>(wq, bq, wk, bk, wv, bv, wp, bt,
                                         Wqkv, Wp, BIASf, bqkv);
    attn_kernel<<<2048, 576, 0, stream>>>(gs, Wqkv, Wp, BIASf, bqkv, bp, (float*)d_out);
}

// Round 3
// 524.858 us; speedup vs baseline: 1.1989x; 1.0452x over previous
//
#include <hip/hip_runtime.h>

// GSSelfAttn: B=2048 windows, N=144 tokens, D=180, H=6 heads, hd=30.
// R3: swapped QK^T (S^T = K x Q^T) -> lane-local softmax, P via 9 ds_write_b64
// into wave-private strip; no Q LDS buffer (transpose through own strip);
// LDS 68352 B -> target 2 blocks/CU; Wp epilogue staged in two halves.

typedef __bf16 bf16_t;
typedef __bf16 bf16x8 __attribute__((ext_vector_type(8)));
typedef __bf16 bf16x4 __attribute__((ext_vector_type(4)));
typedef float f32x4 __attribute__((ext_vector_type(4)));

#define MFMA16(a, b, c) __builtin_amdgcn_mfma_f32_16x16x32_bf16((a), (b), (c), 0, 0, 0)

static __device__ __forceinline__ f32x4 fzero4() {
    f32x4 z; z[0] = 0.f; z[1] = 0.f; z[2] = 0.f; z[3] = 0.f; return z;
}

// ---------------- pack kernel ----------------
// ws layout (bytes):
//   Wqkv  @ 0      : [h][kt6][nt6][lane64][j8] bf16      = 221184 B
//   Wp    @ 221184 : [kt6][nt12][lane64][j8]  bf16       =  73728 B
//   BIASf @ 294912 : [h][wv9][nt9][lane64][r4] bf16      = 248832 B (S^T fragment layout)
//   bqkv  @ 543744 : [h][c96]                 fp32       =   2304 B
__global__ void pack_kernel(const float* __restrict__ wq, const float* __restrict__ bq,
                            const float* __restrict__ wk, const float* __restrict__ bk,
                            const float* __restrict__ wv, const float* __restrict__ bv,
                            const float* __restrict__ wp, const float* __restrict__ bt,
                            bf16_t* __restrict__ Wqkv, bf16_t* __restrict__ Wp,
                            bf16_t* __restrict__ BIASf, float* __restrict__ bqkv)
{
    const int t = blockIdx.x * blockDim.x + threadIdx.x;
    const int stride = gridDim.x * blockDim.x;
    const float scale = 0.18257418583505536f;   // 30^-0.5, folded into Q path

    // Wqkv fragments: kin padded 180->192, per-head cols: [Q32|K32|V32], d padded 30->32
    for (int i = t; i < 6 * 6 * 6 * 512; i += stride) {
        int j = i & 7, lane = (i >> 3) & 63;
        int f = i >> 9;               // [h][kt][nt]
        int nt = f % 6, kt = (f / 6) % 6, h = f / 36;
        int kin = kt * 32 + (lane >> 4) * 8 + j;
        int c = nt * 16 + (lane & 15);       // 0..95
        int sec = c >> 5, d = c & 31;
        float v = 0.f;
        if (kin < 180 && d < 30) {
            int col = h * 30 + d;
            if (sec == 0)      v = wq[kin * 180 + col] * scale;
            else if (sec == 1) v = wk[kin * 180 + col];
            else               v = wv[kin * 180 + col];
        }
        Wqkv[i] = (bf16_t)v;
    }
    // Wp fragments: K index = h*32+d (matches O fragment layout), pad rows d>=30 zero
    for (int i = t; i < 6 * 12 * 512; i += stride) {
        int j = i & 7, lane = (i >> 3) & 63;
        int f = i >> 9;               // [kt][nt]
        int nt = f % 12, kt = f / 12;
        int kin = kt * 32 + (lane >> 4) * 8 + j;
        int hh = kin >> 5, d = kin & 31;
        int cout = nt * 16 + (lane & 15);
        float v = 0.f;
        if (d < 30 && cout < 180) v = wp[(hh * 30 + d) * 180 + cout];
        Wp[i] = (bf16_t)v;
    }
    // relative-position bias in S^T-fragment layout:
    // BIASf[(((h*9+wv)*9+nt)*64 + lane)*4 + r] = bias[h][q=wv*16+(lane&15)][k=nt*16+(lane>>4)*4+r]
    for (int i = t; i < 6 * 9 * 9 * 64; i += stride) {
        int lane = i & 63;
        int f = i >> 6;               // [h][wv][nt]
        int nt = f % 9, wvq = (f / 9) % 9, h = f / 81;
        int q = wvq * 16 + (lane & 15);
        int qi = q / 12, qj = q % 12;
        #pragma unroll
        for (int r = 0; r < 4; ++r) {
            int k = nt * 16 + (lane >> 4) * 4 + r;
            int ki = k / 12, kj = k % 12;
            int rel = (qi - ki + 11) * 23 + (qj - kj + 11);
            BIASf[i * 4 + r] = (bf16_t)bt[rel * 6 + h];
        }
    }
    // packed qkv bias (scale folded into q part)
    for (int i = t; i < 576; i += stride) {
        int c = i % 96, h = i / 96;
        int sec = c >> 5, d = c & 31;
        float v = 0.f;
        if (d < 30) {
            if (sec == 0)      v = bq[h * 30 + d] * scale;
            else if (sec == 1) v = bk[h * 30 + d];
            else               v = bv[h * 30 + d];
        }
        bqkv[i] = v;
    }
}

// ---------------- fused attention kernel ----------------
// block = 576 threads = 9 waves; wave w owns M-strip rows [16w, 16w+16)
// LDS map (total 68352 B):
//   W/P  @ 0     : max(Wqkv head stage 36864, 9 P strips [16][168] bf16 = 48384,
//                      Wp half stage 36864)
//   K    @ 48384 : [144][32] bf16, stride 64 B, swizzle byte^=((row&6)<<3)  (9216 B)
//   Vt   @ 57600 : [32][168] bf16 (d-major, token cols 144..159 zeroed)    (10752 B)
__global__ __launch_bounds__(576, 5)
void attn_kernel(const float* __restrict__ gs,
                 const bf16_t* __restrict__ Wqkv, const bf16_t* __restrict__ Wp,
                 const bf16_t* __restrict__ BIASf, const float* __restrict__ bqkv,
                 const float* __restrict__ bp, float* __restrict__ out)
{
    __shared__ __align__(16) unsigned char smem[68352];

    const int tid = threadIdx.x;
    const int lane = tid & 63;
    const int wv = tid >> 6;          // wave id = M-strip 0..8
    const int l15 = lane & 15;
    const int lg = lane >> 4;         // 0..3
    const int win = blockIdx.x;
    const float* __restrict__ gsw = gs + (size_t)win * 25920;

    constexpr int WP_BASE = 0;
    constexpr int K_BASE  = 48384;
    constexpr int VT_BASE = 57600;

    // ---- gs A-fragments into registers: row = 16*wv + l15, k-tile kt ----
    bf16x8 xa[6];
    {
        const int row = wv * 16 + l15;
        const float4* __restrict__ g4 = (const float4*)(gsw + row * 180);
        #pragma unroll
        for (int kt = 0; kt < 6; ++kt) {
            const int c0 = kt * 32 + lg * 8;
            float4 lo = {0.f, 0.f, 0.f, 0.f}, hi = {0.f, 0.f, 0.f, 0.f};
            if (c0 + 4 <= 180) lo = g4[c0 >> 2];
            if (c0 + 8 <= 180) hi = g4[(c0 >> 2) + 1];
            bf16x8 v;
            v[0] = (bf16_t)lo.x; v[1] = (bf16_t)lo.y; v[2] = (bf16_t)lo.z; v[3] = (bf16_t)lo.w;
            v[4] = (bf16_t)hi.x; v[5] = (bf16_t)hi.y; v[6] = (bf16_t)hi.z; v[7] = (bf16_t)hi.w;
            xa[kt] = v;
        }
    }
    // zero Vt pad token-cols 144..159 once (rows never clobbered afterwards)
    if (tid < 512) {
        int d = tid >> 4, c = 144 + (tid & 15);
        *(bf16_t*)(smem + VT_BASE + d * 336 + c * 2) = (bf16_t)0.f;
    }

    bf16x8 ao[6];                     // per-head O A-fragments (persistent)
    char* const pb = (char*)smem + WP_BASE + wv * 5376;   // wave-private strip

    #pragma unroll
    for (int h = 0; h < 6; ++h) {
        __syncthreads();              // prior head's K/Vt/strips fully consumed
        // ---- stage this head's packed weights (36864 B) ----
        {
            const char* __restrict__ src = (const char*)Wqkv + h * 36864;
            #pragma unroll
            for (int i = 0; i < 4; ++i) {
                const int off = (tid + i * 576) * 16;
                *(int4*)(smem + WP_BASE + off) = *(const int4*)(src + off);
            }
        }
        __syncthreads();

        // ---- QKV GEMM: acc[nt] = X(strip) @ W[:, nt] ----
        f32x4 acc[6];
        #pragma unroll
        for (int nt = 0; nt < 6; ++nt) acc[nt] = fzero4();
        __builtin_amdgcn_s_setprio(1);
        #pragma unroll
        for (int kt = 0; kt < 6; ++kt) {
            #pragma unroll
            for (int nt = 0; nt < 6; ++nt) {
                bf16x8 bw = *(const bf16x8*)(smem + WP_BASE + ((kt * 6 + nt) * 64 + lane) * 16);
                acc[nt] = MFMA16(xa[kt], bw, acc[nt]);
            }
        }
        __builtin_amdgcn_s_setprio(0);

        // ---- scatter K,V to LDS; Q stays in registers ----
        bf16_t q8[8];
        {
            const int row0 = wv * 16 + lg * 4;
            #pragma unroll
            for (int nt = 0; nt < 6; ++nt) {
                const int c = nt * 16 + l15;         // 0..95
                const float bias = bqkv[h * 96 + c];
                const int sec = nt >> 1;
                const int d32 = ((nt & 1) << 4) + l15;
                #pragma unroll
                for (int r = 0; r < 4; ++r) {
                    const int rr = row0 + r;
                    const bf16_t bvl = (bf16_t)(acc[nt][r] + bias);
                    if (sec == 0)
                        q8[(nt & 1) * 4 + r] = bvl;
                    else if (sec == 1)
                        *(bf16_t*)(smem + K_BASE + rr * 64 + ((d32 * 2) ^ ((rr & 6) << 3))) = bvl;
                    else
                        *(bf16_t*)(smem + VT_BASE + d32 * 336 + rr * 2) = bvl;
                }
            }
        }
        __syncthreads();              // K/Vt visible; all W reads done (strips writable)

        // ---- Q transpose through own strip -> B-fragment aq ----
        #pragma unroll
        for (int r = 0; r < 4; ++r) {
            const int row = lg * 4 + r;
            const int swz = (row & 6) << 3;
            *(bf16_t*)(pb + row * 64 + ((l15 * 2) ^ swz))        = q8[r];
            *(bf16_t*)(pb + row * 64 + ((l15 * 2 + 32) ^ swz))   = q8[4 + r];
        }
        asm volatile("" ::: "memory");
        bf16x8 aq = *(const bf16x8*)(pb + l15 * 64 + ((lg * 16) ^ ((l15 & 6) << 3)));

        // ---- S^T = K Q^T (+bias): lane holds S[k=nt*16+lg*4+r][q=wv*16+l15] ----
        f32x4 s[9];
        __builtin_amdgcn_s_setprio(1);
        #pragma unroll
        for (int nt = 0; nt < 9; ++nt) {
            const int krow = nt * 16 + l15;
            bf16x8 kf = *(const bf16x8*)(smem + K_BASE + krow * 64 + ((lg * 16) ^ ((krow & 6) << 3)));
            s[nt] = MFMA16(kf, aq, fzero4());
        }
        __builtin_amdgcn_s_setprio(0);
        #pragma unroll
        for (int nt = 0; nt < 9; ++nt) {
            bf16x4 b4 = *(const bf16x4*)(BIASf + (size_t)((((h * 9 + wv) * 9 + nt) * 64 + lane) * 4));
            #pragma unroll
            for (int r = 0; r < 4; ++r) s[nt][r] += (float)b4[r];
        }

        // ---- lane-local softmax over this lane's fixed q ----
        float m = s[0][0];
        #pragma unroll
        for (int nt = 0; nt < 9; ++nt)
            #pragma unroll
            for (int r = 0; r < 4; ++r) m = fmaxf(m, s[nt][r]);
        m = fmaxf(m, __shfl_xor(m, 16, 64));
        m = fmaxf(m, __shfl_xor(m, 32, 64));
        float sum = 0.f;
        #pragma unroll
        for (int nt = 0; nt < 9; ++nt)
            #pragma unroll
            for (int r = 0; r < 4; ++r) {
                float p = exp2f((s[nt][r] - m) * 1.4426950408889634f);
                s[nt][r] = p;
                sum += p;
            }
        sum += __shfl_xor(sum, 16, 64);
        sum += __shfl_xor(sum, 32, 64);
        const float rinv = 1.f / sum;  // normalization deferred to O epilogue

        // ---- P -> own strip [q16][k168] bf16 (9x ds_write_b64) ----
        #pragma unroll
        for (int nt = 0; nt < 9; ++nt) {
            bf16x4 pw;
            pw[0] = (bf16_t)s[nt][0]; pw[1] = (bf16_t)s[nt][1];
            pw[2] = (bf16_t)s[nt][2]; pw[3] = (bf16_t)s[nt][3];
            *(bf16x4*)(pb + l15 * 336 + nt * 32 + lg * 8) = pw;
        }
        // zero pad k=144..159 (clobbered by W stage each head)
        *(f32x4*)(pb + l15 * 336 + 288 + (lg & 1) * 16) = fzero4();
        asm volatile("" ::: "memory");

        // ---- PV: O(strip)[16x32] = P[16x160] @ Vt^T ----
        f32x4 o0 = fzero4(), o1 = fzero4();
        __builtin_amdgcn_s_setprio(1);
        #pragma unroll
        for (int kt = 0; kt < 5; ++kt) {
            bf16x8 ap  = *(const bf16x8*)(pb + l15 * 336 + kt * 64 + lg * 16);
            bf16x8 bv0 = *(const bf16x8*)(smem + VT_BASE + l15 * 336 + kt * 64 + lg * 16);
            bf16x8 bv1 = *(const bf16x8*)(smem + VT_BASE + (16 + l15) * 336 + kt * 64 + lg * 16);
            o0 = MFMA16(ap, bv0, o0);
            o1 = MFMA16(ap, bv1, o1);
        }
        __builtin_amdgcn_s_setprio(0);

        // ---- normalize + transpose 16x32 O slice through strip -> ao[h] ----
        asm volatile("" ::: "memory");
        #pragma unroll
        for (int r = 0; r < 4; ++r) {
            const float rq = __shfl(rinv, lg * 4 + r, 16);
            const int row = lg * 4 + r;
            const int swz = (row & 6) << 3;
            *(bf16_t*)(pb + row * 64 + ((l15 * 2) ^ swz))      = (bf16_t)(o0[r] * rq);
            *(bf16_t*)(pb + row * 64 + ((l15 * 2 + 32) ^ swz)) = (bf16_t)(o1[r] * rq);
        }
        asm volatile("" ::: "memory");
        ao[h] = *(const bf16x8*)(pb + l15 * 64 + ((lg * 16) ^ ((l15 & 6) << 3)));
    }

    // ---- output projection: out = O @ Wp + bp, Wp staged in two halves ----
    f32x4 accp[12];
    #pragma unroll
    for (int nt = 0; nt < 12; ++nt) accp[nt] = fzero4();
    #pragma unroll
    for (int half = 0; half < 2; ++half) {
        __syncthreads();              // strips consumed / previous half reads done
        {
            const char* __restrict__ src = (const char*)Wp + half * 36864;
            #pragma unroll
            for (int i = 0; i < 4; ++i) {
                const int off = (tid + i * 576) * 16;
                *(int4*)(smem + WP_BASE + off) = *(const int4*)(src + off);
            }
        }
        __syncthreads();
        __builtin_amdgcn_s_setprio(1);
        #pragma unroll
        for (int kt = 0; kt < 3; ++kt) {
            #pragma unroll
            for (int nt = 0; nt < 12; ++nt) {
                bf16x8 bw = *(const bf16x8*)(smem + WP_BASE + ((kt * 12 + nt) * 64 + lane) * 16);
                accp[nt] = MFMA16(ao[half * 3 + kt], bw, accp[nt]);
            }
        }
        __builtin_amdgcn_s_setprio(0);
    }
    {
        float* __restrict__ og = out + (size_t)win * 25920;
        #pragma unroll
        for (int nt = 0; nt < 12; ++nt) {
            const int col = nt * 16 + l15;
            if (col < 180) {
                const float bias = bp[col];
                #pragma unroll
                for (int r = 0; r < 4; ++r) {
                    const int row = wv * 16 + lg * 4 + r;
                    og[row * 180 + col] = accp[nt][r] + bias;
                }
            }
        }
    }
}

extern "C" void kernel_launch(void* const* d_in, const int* in_sizes, int n_in,
                              void* d_out, int out_size, void* d_ws, size_t ws_size,
                              hipStream_t stream) {
    const float* gs = (const float*)d_in[0];
    const float* wq = (const float*)d_in[1];
    const float* bq = (const float*)d_in[2];
    const float* wk = (const float*)d_in[3];
    const float* bk = (const float*)d_in[4];
    const float* wv = (const float*)d_in[5];
    const float* bv = (const float*)d_in[6];
    const float* wp = (const float*)d_in[7];
    const float* bp = (const float*)d_in[8];
    const float* bt = (const float*)d_in[9];

    char* ws = (char*)d_ws;
    bf16_t* Wqkv  = (bf16_t*)(ws);
    bf16_t* Wp    = (bf16_t*)(ws + 221184);
    bf16_t* BIASf = (bf16_t*)(ws + 294912);
    float*  bqkv  = (float*)(ws + 543744);

    pack_kernel<<<256, 256, 0, stream>>>(wq, bq, wk, bk, wv, bv, wp, bt,
                                         Wqkv, Wp, BIASf, bqkv);
    attn_kernel<<<2048, 576, 0, stream>>>(gs, Wqkv, Wp, BIASf, bqkv, bp, (float*)d_out);
}